// Round 3
// baseline (819.664 us; speedup 1.0000x reference)
//
#include <hip/hip_runtime.h>
#include <stdint.h>

#define L_DIM 2048
#define B_DIM 16
#define D_DIM 1024
#define M_DIM 32768              // L*B
#define K_DIM 1024               // D
#define N_DIM 3072               // 3D
#define SCALE_X 1.7320508075688772f

typedef __attribute__((ext_vector_type(8))) short short8;
typedef __attribute__((ext_vector_type(4))) float f32x4;

__device__ __forceinline__ float bf2f(uint32_t b) {
    union { uint32_t u; float f; } v; v.u = b << 16; return v.f;
}
__device__ __forceinline__ uint16_t f2bf(float f) {
    union { float f; uint32_t u; } v; v.f = f;
    uint32_t u = v.u;
    return (uint16_t)((u + 0x7FFFu + ((u >> 16) & 1u)) >> 16);  // RNE
}

// ---- prep: weight (K x N fp32) -> Wt (N x K bf16), i.e. B^T ----
__global__ void prep_w_kernel(const float* __restrict__ w, uint16_t* __restrict__ wt) {
    int i = blockIdx.x * 256 + threadIdx.x;       // over K*N, coalesced read
    int k = i / N_DIM;
    int n = i - k * N_DIM;
    wt[n * K_DIM + k] = f2bf(w[i]);
}

// ---- GEMM: u01 plane (u0,u1 packed per d, lives in d_out) + u2 plane (ws) ----
// 128x128 tile, BK=32, 4 waves each computing 4x4 frags of 16x16x32 bf16 MFMA.
// A is fp32 x, converted to bf16 in-register during staging.
__global__ void __launch_bounds__(256)
gemm_kernel(const float* __restrict__ A32,    // x fp32, M x K
            const uint16_t* __restrict__ Bt,  // Wt bf16, N x K
            uint16_t* __restrict__ u01,       // M x D x 2 (u0 low, u1 high) — aliases d_out h region
            uint16_t* __restrict__ u2p)       // M x D (ws)
{
    __shared__ uint16_t As[128 * 32];
    __shared__ uint16_t Bs[128 * 32];

    // supertile swizzle: groups of 8 m-tiles x all 24 n-tiles
    int bid = blockIdx.x;
    int mg = bid / 192;
    int tt = bid - mg * 192;
    int ntile = tt >> 3;
    int mtile = mg * 8 + (tt & 7);
    int m0 = mtile * 128;
    int n0 = ntile * 128;

    int t = threadIdx.x;
    int lane = t & 63;
    int w = t >> 6;
    int wm = (w >> 1) * 64;
    int wn = (w & 1) * 64;

    f32x4 acc[4][4] = {};

    int frow = lane & 15;
    int fk = (lane >> 4) * 8;

    for (int kt = 0; kt < K_DIM; kt += 32) {
        // A: 128x32 fp32 = 1024 float4 chunks, 4 per thread; convert to bf16
#pragma unroll
        for (int c = 0; c < 4; c++) {
            int idx = c * 256 + t;
            int row = idx >> 3;            // 8 chunks of 4 floats per 32-wide row
            int ko = (idx & 7) * 4;
            float4 v = *(const float4*)(A32 + (size_t)(m0 + row) * K_DIM + kt + ko);
            ushort4 o;
            o.x = f2bf(v.x); o.y = f2bf(v.y); o.z = f2bf(v.z); o.w = f2bf(v.w);
            *(ushort4*)(As + row * 32 + ko) = o;
        }
        // B: 128x32 bf16 = 512 short8 chunks, 2 per thread
#pragma unroll
        for (int c = 0; c < 2; c++) {
            int idx = c * 256 + t;
            int row = idx >> 2;
            int ko = (idx & 3) * 8;
            short8 v = *(const short8*)(Bt + (size_t)(n0 + row) * K_DIM + kt + ko);
            *(short8*)(Bs + row * 32 + ko) = v;
        }
        __syncthreads();

        short8 af[4], bfr[4];
#pragma unroll
        for (int i = 0; i < 4; i++) {
            af[i]  = *(const short8*)(As + (wm + i * 16 + frow) * 32 + fk);
            bfr[i] = *(const short8*)(Bs + (wn + i * 16 + frow) * 32 + fk);
        }
#pragma unroll
        for (int i = 0; i < 4; i++)
#pragma unroll
            for (int j = 0; j < 4; j++)
                acc[i][j] = __builtin_amdgcn_mfma_f32_16x16x32_bf16(af[i], bfr[j], acc[i][j], 0, 0, 0);
        __syncthreads();
    }

    // epilogue: C/D layout col=lane&15, row=(lane>>4)*4+reg  [m89-verified]
    int colf = lane & 15;
    int rowq = (lane >> 4) * 4;
#pragma unroll
    for (int i = 0; i < 4; i++) {
#pragma unroll
        for (int j = 0; j < 4; j++) {
            int gcol = n0 + wn + j * 16 + colf;      // n = 3*d + comp (reshape (...,3072)->(...,1024,3))
            int dq = gcol / 3;
            int cm = gcol - dq * 3;
#pragma unroll
            for (int r = 0; r < 4; r++) {
                int grow = m0 + wm + i * 16 + rowq + r;
                uint16_t v = f2bf(acc[i][j][r]);
                if (cm < 2) u01[(size_t)grow * 2048 + dq * 2 + cm] = v;
                else        u2p[(size_t)grow * 1024 + dq] = v;
            }
        }
    }
}

// ---- scan: one thread per (b,d) chain, P-deep register prefetch ----
// u01 aliases the fp32 h output region (same 4B/elem indexing); each thread
// reads u01 P steps ahead of its h writes and cids never share addresses.
__global__ void __launch_bounds__(64)
scan_kernel(const uint32_t* u01,              // M x D of {u0,u1} (aliases out)
            const uint16_t* __restrict__ u2p, // M x D
            const float* __restrict__ x,      // fp32 x (L,B,D)
            const float* __restrict__ c0,
            const float* __restrict__ wc,
            const float* __restrict__ bias,
            float* out)                       // h (L,B,D) fp32 then c_final (B,D) fp32
{
    int cid = blockIdx.x * 64 + threadIdx.x;       // b*1024 + d
    int d = cid & (D_DIM - 1);
    float fw = wc[d], rw = wc[D_DIM + d];
    float fb = bias[d], rb = bias[D_DIM + d];
    float c = c0[cid];

    constexpr int P = 16;
    const int STEP = B_DIM * D_DIM;                // 16384
    uint32_t b01[P];
    uint16_t b2v[P];
    float bx[P];
#pragma unroll
    for (int j = 0; j < P; j++) {
        b01[j] = u01[cid + j * STEP];
        b2v[j] = u2p[cid + j * STEP];
        bx[j]  = x[cid + j * STEP];
    }

    for (int lb = 0; lb < L_DIM; lb += P) {
#pragma unroll
        for (int j = 0; j < P; j++) {
            int l = lb + j;
            uint32_t v01 = b01[j];
            float u2 = bf2f((uint32_t)b2v[j]);
            float xp = bx[j] * SCALE_X;

            int ln = l + P; if (ln > L_DIM - 1) ln = L_DIM - 1;
            int ri = cid + ln * STEP;
            b01[j] = u01[ri];
            b2v[j] = u2p[ri];
            bx[j]  = x[ri];

            float u0 = bf2f(v01 & 0xFFFFu);
            float u1 = bf2f(v01 >> 16);

            float ef = __expf(-(u1 + fb + c * fw));
            float er = __expf(-(u2 + rb + c * rw));
            float f = __builtin_amdgcn_rcpf(1.0f + ef);
            float r = __builtin_amdgcn_rcpf(1.0f + er);
            c = u0 + (c - u0) * f;
            float h = xp + (c - xp) * r;
            out[l * STEP + cid] = h;
        }
    }
    out[L_DIM * STEP + cid] = c;
}

extern "C" void kernel_launch(void* const* d_in, const int* in_sizes, int n_in,
                              void* d_out, int out_size, void* d_ws, size_t ws_size,
                              hipStream_t stream) {
    const float* x    = (const float*)d_in[0];
    const float* c0   = (const float*)d_in[1];
    const float* w    = (const float*)d_in[2];
    const float* wc   = (const float*)d_in[3];
    const float* bias = (const float*)d_in[4];

    // ws layout (total 70 MB): wt 6 MB | u2 64 MB
    uint16_t* wt  = (uint16_t*)d_ws;
    uint16_t* u2p = (uint16_t*)((char*)d_ws + 6291456);

    // u01 (M*D uint32) aliases the h region of d_out (same size & indexing).
    uint16_t* u01 = (uint16_t*)d_out;
    float* out = (float*)d_out;

    prep_w_kernel<<<(K_DIM * N_DIM) / 256, 256, 0, stream>>>(w, wt);
    gemm_kernel<<<(M_DIM / 128) * (N_DIM / 128), 256, 0, stream>>>(x, wt, u01, u2p);
    scan_kernel<<<(B_DIM * D_DIM) / 64, 64, 0, stream>>>((const uint32_t*)u01, u2p, x,
                                                         c0, wc, bias, out);
}